// Round 2
// baseline (858.188 us; speedup 1.0000x reference)
//
#include <hip/hip_runtime.h>
#include <hip/hip_bf16.h>

typedef __bf16 bf16;
typedef __attribute__((ext_vector_type(8))) __bf16 bf16x8;
typedef __attribute__((ext_vector_type(4))) __bf16 bf16x4;
typedef __attribute__((ext_vector_type(4))) float f32x4;

#define BATCH 64
#define R2 256
#define CIN 256
#define CH 128
#define C_OUT 256
#define FLAT_PH 16384
#define FLAT_Z 4096
#define NE 1024
#define ED 128

#define MFMA(a,b,c) __builtin_amdgcn_mfma_f32_16x16x32_bf16(a,b,c,0,0,0)

__device__ inline float siluf(float v){ return v / (1.0f + __expf(-v)); }

// split 8 contiguous fp32 into hi/lo bf16x8 (p must be 16B aligned)
__device__ inline void split8(const float* __restrict__ p, bf16x8& h, bf16x8& l){
  f32x4 a = *(const f32x4*)p;
  f32x4 b = *(const f32x4*)(p+4);
#pragma unroll
  for (int j=0;j<4;j++){ bf16 hh=(bf16)a[j]; h[j]=hh; l[j]=(bf16)(a[j]-(float)hh); }
#pragma unroll
  for (int j=0;j<4;j++){ bf16 hh=(bf16)b[j]; h[4+j]=hh; l[4+j]=(bf16)(b[j]-(float)hh); }
}

// ---------------- K1: conv_in  h[b][o][p] = sum_c silu(x[b][c][p]) * w[o][c] + bias[o]
// grid (pq=8, b=64), block 256. Block: 32 positions, all 128 outputs. fp32 in/out.
__global__ __launch_bounds__(256) void k1_conv_in(
    const float* __restrict__ x, const float* __restrict__ w, const float* __restrict__ bias,
    float* __restrict__ h)
{
  __shared__ bf16 shi[32][264];  // [p][c]
  __shared__ bf16 slo[32][264];
  int b = blockIdx.y, pq = blockIdx.x, t = threadIdx.x;
  const float* xb = x + (size_t)b*CIN*R2 + pq*32;
#pragma unroll
  for (int i=0;i<8;i++){
    int f = i*256 + t;          // f32x4 units: 256c * 8 units(32p/4)
    int c = f >> 3;
    int po = (f & 7)*4;
    f32x4 v = *(const f32x4*)(xb + (size_t)c*R2 + po);
#pragma unroll
    for (int j=0;j<4;j++){
      float s = siluf(v[j]);
      bf16 hi = (bf16)s;
      shi[po+j][c] = hi;
      slo[po+j][c] = (bf16)(s - (float)hi);
    }
  }
  __syncthreads();
  int wv = t>>6, lane = t&63, lm = lane&15, lq = lane>>4;
  f32x4 acc[2][2];
#pragma unroll
  for (int i=0;i<2;i++)
#pragma unroll
    for (int j=0;j<2;j++) acc[i][j] = (f32x4){0.f,0.f,0.f,0.f};
  for (int ks=0; ks<8; ks++){
    int kc = ks*32 + lq*8;
    bf16x8 wh[2], wl[2], bh[2], bl[2];
#pragma unroll
    for (int i=0;i<2;i++){
      int o = (wv*2+i)*16 + lm;
      split8(w + (size_t)o*CIN + kc, wh[i], wl[i]);
    }
#pragma unroll
    for (int j=0;j<2;j++){
      int p = j*16 + lm;
      bh[j] = *(const bf16x8*)(&shi[p][kc]);
      bl[j] = *(const bf16x8*)(&slo[p][kc]);
    }
#pragma unroll
    for (int i=0;i<2;i++)
#pragma unroll
      for (int j=0;j<2;j++){
        acc[i][j] = MFMA(wh[i], bh[j], acc[i][j]);
        acc[i][j] = MFMA(wl[i], bh[j], acc[i][j]);
        acc[i][j] = MFMA(wh[i], bl[j], acc[i][j]);
      }
  }
#pragma unroll
  for (int i=0;i<2;i++)
#pragma unroll
    for (int j=0;j<2;j++)
#pragma unroll
      for (int r=0;r<4;r++){
        int o = (wv*2+i)*16 + lq*4 + r;
        int p = pq*32 + j*16 + lm;
        h[(size_t)b*CH*R2 + (size_t)o*R2 + p] = acc[i][j][r] + bias[o];
      }
}

// ---------------- K2: LayerNorm over h[b][0:64][:], write hn as hi/lo bf16. grid 64
__global__ __launch_bounds__(256) void k2_ln(
    const float* __restrict__ h, const float* __restrict__ lnw, const float* __restrict__ lnb,
    bf16* __restrict__ hnhi, bf16* __restrict__ hnlo)
{
  int b = blockIdx.x, t = threadIdx.x;
  const float* hb = h + (size_t)b*CH*R2;  // first 16384 floats = phylo
  float s = 0.f, sq = 0.f;
#pragma unroll
  for (int i=0;i<16;i++){
    f32x4 v = *(const f32x4*)(hb + (i*256 + t)*4);
    s  += v.x+v.y+v.z+v.w;
    sq += v.x*v.x + v.y*v.y + v.z*v.z + v.w*v.w;
  }
#pragma unroll
  for (int o=32;o>0;o>>=1){ s += __shfl_down(s,o,64); sq += __shfl_down(sq,o,64); }
  __shared__ float rs[4], rq[4], stats[2];
  int wv = t>>6, lane = t&63;
  if (lane==0){ rs[wv]=s; rq[wv]=sq; }
  __syncthreads();
  if (t==0){
    float S = rs[0]+rs[1]+rs[2]+rs[3], Q = rq[0]+rq[1]+rq[2]+rq[3];
    float mu = S * (1.f/16384.f);
    float var = Q * (1.f/16384.f) - mu*mu;
    stats[0] = mu; stats[1] = rsqrtf(var + 1e-5f);
  }
  __syncthreads();
  float mu = stats[0], rstd = stats[1];
#pragma unroll
  for (int i=0;i<16;i++){
    int f = (i*256+t)*4;
    f32x4 v = *(const f32x4*)(hb + f);
    f32x4 gw = *(const f32x4*)(lnw + f);
    f32x4 gb = *(const f32x4*)(lnb + f);
    bf16x4 hv, lv;
#pragma unroll
    for (int j=0;j<4;j++){
      float hn = (v[j]-mu)*rstd*gw[j] + gb[j];
      bf16 hi = (bf16)hn;
      hv[j] = hi;
      lv[j] = (bf16)(hn - (float)hi);
    }
    *(bf16x4*)(hnhi + (size_t)b*FLAT_PH + f) = hv;
    *(bf16x4*)(hnlo + (size_t)b*FLAT_PH + f) = lv;
  }
}

// ---------------- K3: part = (Ahi+Alo)[64,16384] @ Wfp32[4096,16384]^T  (K-split)
// grid (nb=32, kb=8), block 256. Block tile: M=64, N=128 (wave 32n), K-chunk 2048.
__global__ __launch_bounds__(256) void k3_gemm1(
    const bf16* __restrict__ Ahi, const bf16* __restrict__ Alo,
    const float* __restrict__ W, float* __restrict__ part)
{
  int t = threadIdx.x, wv = t>>6, lane = t&63, lm = lane&15, lq = lane>>4;
  int n0 = blockIdx.x*128 + wv*32;
  int k0 = blockIdx.y*2048;
  f32x4 acc[4][2];
#pragma unroll
  for (int mt=0;mt<4;mt++)
#pragma unroll
    for (int jt=0;jt<2;jt++) acc[mt][jt] = (f32x4){0.f,0.f,0.f,0.f};
  for (int ks=0; ks<64; ks++){
    int k = k0 + ks*32 + lq*8;
    bf16x8 ah[4], al[4], wh[2], wl[2];
#pragma unroll
    for (int mt=0;mt<4;mt++){
      ah[mt] = *(const bf16x8*)(Ahi + (size_t)(mt*16+lm)*FLAT_PH + k);
      al[mt] = *(const bf16x8*)(Alo + (size_t)(mt*16+lm)*FLAT_PH + k);
    }
#pragma unroll
    for (int jt=0;jt<2;jt++)
      split8(W + (size_t)(n0 + jt*16 + lm)*FLAT_PH + k, wh[jt], wl[jt]);
#pragma unroll
    for (int mt=0;mt<4;mt++)
#pragma unroll
      for (int jt=0;jt<2;jt++){
        acc[mt][jt] = MFMA(ah[mt], wh[jt], acc[mt][jt]);
        acc[mt][jt] = MFMA(al[mt], wh[jt], acc[mt][jt]);
        acc[mt][jt] = MFMA(ah[mt], wl[jt], acc[mt][jt]);
      }
  }
  float* cp = part + (size_t)blockIdx.y*BATCH*FLAT_Z;
#pragma unroll
  for (int mt=0;mt<4;mt++)
#pragma unroll
    for (int jt=0;jt<2;jt++)
#pragma unroll
      for (int r=0;r<4;r++){
        int m = mt*16 + lq*4 + r;
        int n = n0 + jt*16 + lm;
        cp[(size_t)m*FLAT_Z + n] = acc[mt][jt][r];
      }
}

// ---------------- K3r: z = sum_kb part + bias.  grid 256 (65536 float4)
__global__ __launch_bounds__(256) void k3r(const float* __restrict__ part,
    const float* __restrict__ bias, float* __restrict__ z)
{
  int f4 = blockIdx.x*256 + threadIdx.x;
  f32x4 s = (f32x4){0.f,0.f,0.f,0.f};
#pragma unroll
  for (int kb=0;kb<8;kb++){
    f32x4 v = *(const f32x4*)(part + (size_t)kb*BATCH*FLAT_Z + (size_t)f4*4);
    s.x+=v.x; s.y+=v.y; s.z+=v.z; s.w+=v.w;
  }
  int n = (f4*4) & (FLAT_Z-1);
  f32x4 bv = *(const f32x4*)(bias + n);
  s.x += bv.x; s.y += bv.y; s.z += bv.z; s.w += bv.w;
  *(f32x4*)(z + (size_t)f4*4) = s;
}

// ---------------- K3a: cc[n] = sum_e codebook[n][e]^2.  grid 4
__global__ __launch_bounds__(256) void k3a_cc(const float* __restrict__ cb, float* __restrict__ cc){
  int n = blockIdx.x*256 + threadIdx.x;
  const float* row = cb + (size_t)n*ED;
  float s = 0.f;
#pragma unroll
  for (int i=0;i<32;i++){
    f32x4 v = *(const f32x4*)(row + i*4);
    s += v.x*v.x + v.y*v.y + v.z*v.z + v.w*v.w;
  }
  cc[n] = s;
}

// ---------------- K4: VQ partial argmin. grid (nq=4, b=64), block 256.
__global__ __launch_bounds__(256) void k4_vq(const float* __restrict__ z,
  const float* __restrict__ cb, const float* __restrict__ cc,
  float* __restrict__ vqd, int* __restrict__ vqn)
{
  __shared__ float zt[32][132];   // [vec][e]
  int b = blockIdx.y, nq = blockIdx.x, t = threadIdx.x;
  const float* zb = z + (size_t)b*FLAT_Z;
#pragma unroll
  for (int i=0;i<16;i++){
    int f = i*256 + t;
    zt[f & 31][f >> 5] = zb[f];
  }
  __syncthreads();
  int vec = t>>3, nc = t&7;
  const float* zv = zt[vec];
  float bd = 3.4e38f; int bn = 0;
  int nbase = nq*256 + nc*32;
  for (int ni=0;ni<32;ni++){
    int n = nbase + ni;
    const float* row = cb + (size_t)n*ED;
    float dot = 0.f;
#pragma unroll
    for (int e=0;e<128;e+=4){
      f32x4 cv = *(const f32x4*)(row+e);
      f32x4 zz = *(const f32x4*)(zv+e);
      dot += zz.x*cv.x + zz.y*cv.y + zz.z*cv.z + zz.w*cv.w;
    }
    float d = cc[n] - 2.f*dot;   // |z|^2 omitted: constant per vec
    if (d < bd){ bd = d; bn = n; }
  }
#pragma unroll
  for (int off=1; off<8; off<<=1){
    float od = __shfl_xor(bd, off, 64);
    int on = __shfl_xor(bn, off, 64);
    if (od < bd || (od == bd && on < bn)){ bd = od; bn = on; }
  }
  if (nc == 0){
    int v = b*32 + vec;
    vqd[v*4+nq] = bd; vqn[v*4+nq] = bn;
  }
}

// ---------------- K4r: combine 4 nq-partials per vector. grid 8
__global__ void k4r(const float* __restrict__ vqd, const int* __restrict__ vqn, int* __restrict__ idx){
  int v = blockIdx.x*256 + threadIdx.x;
  float bd = vqd[v*4]; int bn = vqn[v*4];
#pragma unroll
  for (int q=1;q<4;q++){
    float d = vqd[v*4+q]; int n = vqn[v*4+q];
    if (d < bd || (d == bd && n < bn)){ bd = d; bn = n; }
  }
  idx[v] = bn;
}

// ---------------- K5a: gather zq hi/lo + loss accumulation. grid 64
__global__ __launch_bounds__(256) void k5a(const int* __restrict__ idx,
  const float* __restrict__ cb, const float* __restrict__ z,
  bf16* __restrict__ zqhi, bf16* __restrict__ zqlo, float* __restrict__ lossacc)
{
  __shared__ int il[32];
  int b = blockIdx.x, t = threadIdx.x;
  if (t < 32) il[t] = idx[b*32 + t];
  __syncthreads();
  int cl = t & 31, ec = t >> 5;
  const float* row = cb + (size_t)il[cl]*ED + ec*16;
  const float* zb = z + (size_t)b*FLAT_Z;
  bf16* zqh = zqhi + (size_t)b*FLAT_Z;
  bf16* zql = zqlo + (size_t)b*FLAT_Z;
  float acc = 0.f;
#pragma unroll
  for (int j=0;j<16;j++){
    int e = ec*16 + j;
    float c = row[j];
    float d = c - zb[e*32 + cl];
    bf16 hi = (bf16)c;
    zqh[e*32 + cl] = hi;
    zql[e*32 + cl] = (bf16)(c - (float)hi);
    acc += d*d;
  }
#pragma unroll
  for (int o=32;o>0;o>>=1) acc += __shfl_down(acc, o, 64);
  __shared__ float ra[4];
  int wv = t>>6, lane = t&63;
  if (lane==0) ra[wv] = acc;
  __syncthreads();
  if (t==0) atomicAdd(lossacc, ra[0]+ra[1]+ra[2]+ra[3]);
}

// ---------------- K5: part = zq[64,4096] @ Wfp32[16384,4096]^T (K-split)
// grid (nb=128, kb=2), block 256. Block tile: M=64, N=128, K-chunk 2048.
__global__ __launch_bounds__(256) void k5_gemm2(
    const bf16* __restrict__ Ahi, const bf16* __restrict__ Alo,
    const float* __restrict__ W, float* __restrict__ part)
{
  int t = threadIdx.x, wv = t>>6, lane = t&63, lm = lane&15, lq = lane>>4;
  int n0 = blockIdx.x*128 + wv*32;
  int k0 = blockIdx.y*2048;
  f32x4 acc[4][2];
#pragma unroll
  for (int mt=0;mt<4;mt++)
#pragma unroll
    for (int jt=0;jt<2;jt++) acc[mt][jt] = (f32x4){0.f,0.f,0.f,0.f};
  for (int ks=0; ks<64; ks++){
    int k = k0 + ks*32 + lq*8;
    bf16x8 ah[4], al[4], wh[2], wl[2];
#pragma unroll
    for (int mt=0;mt<4;mt++){
      ah[mt] = *(const bf16x8*)(Ahi + (size_t)(mt*16+lm)*FLAT_Z + k);
      al[mt] = *(const bf16x8*)(Alo + (size_t)(mt*16+lm)*FLAT_Z + k);
    }
#pragma unroll
    for (int jt=0;jt<2;jt++)
      split8(W + (size_t)(n0 + jt*16 + lm)*FLAT_Z + k, wh[jt], wl[jt]);
#pragma unroll
    for (int mt=0;mt<4;mt++)
#pragma unroll
      for (int jt=0;jt<2;jt++){
        acc[mt][jt] = MFMA(ah[mt], wh[jt], acc[mt][jt]);
        acc[mt][jt] = MFMA(al[mt], wh[jt], acc[mt][jt]);
        acc[mt][jt] = MFMA(ah[mt], wl[jt], acc[mt][jt]);
      }
  }
  float* cp = part + (size_t)blockIdx.y*BATCH*FLAT_PH;
#pragma unroll
  for (int mt=0;mt<4;mt++)
#pragma unroll
    for (int jt=0;jt<2;jt++)
#pragma unroll
      for (int r=0;r<4;r++){
        int m = mt*16 + lq*4 + r;
        int n = n0 + jt*16 + lm;
        cp[(size_t)m*FLAT_PH + n] = acc[mt][jt][r];
      }
}

// ---------------- K5r: hout = sum_kb part + bias. grid 1024 (262144 float4)
__global__ __launch_bounds__(256) void k5r(const float* __restrict__ part,
    const float* __restrict__ bias, float* __restrict__ hout)
{
  int f4 = blockIdx.x*256 + threadIdx.x;
  f32x4 s = (f32x4){0.f,0.f,0.f,0.f};
#pragma unroll
  for (int kb=0;kb<2;kb++){
    f32x4 v = *(const f32x4*)(part + (size_t)kb*BATCH*FLAT_PH + (size_t)f4*4);
    s.x+=v.x; s.y+=v.y; s.z+=v.z; s.w+=v.w;
  }
  int n = (f4*4) & (FLAT_PH-1);
  f32x4 bv = *(const f32x4*)(bias + n);
  s.x += bv.x; s.y += bv.y; s.z += bv.z; s.w += bv.w;
  *(f32x4*)(hout + (size_t)f4*4) = s;
}

// ---------------- K6: conv_out over concat(silu(hout), silu(h_img)). grid (pq=4, b=64)
__global__ __launch_bounds__(256) void k6_conv_out(
  const float* __restrict__ hout, const float* __restrict__ h,
  const float* __restrict__ w, const float* __restrict__ bias, float* __restrict__ out)
{
  __shared__ bf16 shi[64][136];
  __shared__ bf16 slo[64][136];
  int b = blockIdx.y, pq = blockIdx.x, t = threadIdx.x;
#pragma unroll
  for (int i=0;i<8;i++){
    int f = i*256 + t;           // float4 units: 128c * 16 units(64p/4)
    int c = f >> 4;
    int po = (f & 15)*4;
    const float* src = (c < 64) ? (hout + (size_t)b*FLAT_PH + (size_t)c*R2)
                                : (h    + (size_t)b*CH*R2   + (size_t)c*R2);
    f32x4 v = *(const f32x4*)(src + pq*64 + po);
#pragma unroll
    for (int j=0;j<4;j++){
      float s = siluf(v[j]);
      bf16 hi = (bf16)s;
      shi[po+j][c] = hi;
      slo[po+j][c] = (bf16)(s - (float)hi);
    }
  }
  __syncthreads();
  int wv = t>>6, lane = t&63, lm = lane&15, lq = lane>>4;
  f32x4 acc[4][4];
#pragma unroll
  for (int i=0;i<4;i++)
#pragma unroll
    for (int j=0;j<4;j++) acc[i][j] = (f32x4){0.f,0.f,0.f,0.f};
  for (int ks=0; ks<4; ks++){
    int kc = ks*32 + lq*8;
    bf16x8 wh[4], wl[4], bh[4], bl[4];
#pragma unroll
    for (int i=0;i<4;i++){
      int o = (wv*4+i)*16 + lm;
      split8(w + (size_t)o*CH + kc, wh[i], wl[i]);
    }
#pragma unroll
    for (int j=0;j<4;j++){
      int p = j*16 + lm;
      bh[j] = *(const bf16x8*)(&shi[p][kc]);
      bl[j] = *(const bf16x8*)(&slo[p][kc]);
    }
#pragma unroll
    for (int i=0;i<4;i++)
#pragma unroll
      for (int j=0;j<4;j++){
        acc[i][j] = MFMA(wh[i], bh[j], acc[i][j]);
        acc[i][j] = MFMA(wl[i], bh[j], acc[i][j]);
        acc[i][j] = MFMA(wh[i], bl[j], acc[i][j]);
      }
  }
#pragma unroll
  for (int i=0;i<4;i++)
#pragma unroll
    for (int j=0;j<4;j++)
#pragma unroll
      for (int r=0;r<4;r++){
        int o = (wv*4+i)*16 + lq*4 + r;
        int p = pq*64 + j*16 + lm;
        out[(size_t)b*C_OUT*R2 + (size_t)o*R2 + p] = acc[i][j][r] + bias[o];
      }
}

// ---------------- K7: write loss
__global__ void k7_loss(const float* __restrict__ lossacc, float* __restrict__ out){
  if (threadIdx.x == 0)
    out[0] = lossacc[0] * 1.25f / 262144.0f;
}

extern "C" void kernel_launch(void* const* d_in, const int* in_sizes, int n_in,
                              void* d_out, int out_size, void* d_ws, size_t ws_size,
                              hipStream_t stream)
{
  (void)in_sizes; (void)n_in; (void)out_size; (void)ws_size;
  const float* x          = (const float*)d_in[0];
  const float* conv_in_w  = (const float*)d_in[1];
  const float* conv_in_b  = (const float*)d_in[2];
  const float* ln_w       = (const float*)d_in[3];
  const float* ln_b       = (const float*)d_in[4];
  const float* mlp_in_w   = (const float*)d_in[5];
  const float* mlp_in_b   = (const float*)d_in[6];
  const float* codebook   = (const float*)d_in[7];
  const float* mlp_out_w  = (const float*)d_in[8];
  const float* mlp_out_b  = (const float*)d_in[9];
  const float* conv_out_w = (const float*)d_in[10];
  const float* conv_out_b = (const float*)d_in[11];

  char* ws = (char*)d_ws;
  const size_t MB = 1u<<20;
  float* h_ws    = (float*)(ws + 0);            // 8 MB  [64][128][256] fp32
  bf16*  hnhi    = (bf16*) (ws + 8*MB);         // 2 MB
  bf16*  hnlo    = (bf16*) (ws + 10*MB);        // 2 MB
  float* part    = (float*)(ws + 12*MB);        // 8 MB (reused by gemm1 & gemm2)
  float* z       = (float*)(ws + 20*MB);        // 1 MB
  float* hout    = (float*)(ws + 21*MB);        // 4 MB
  bf16*  zqhi    = (bf16*) (ws + 25*MB);        // 0.5 MB
  bf16*  zqlo    = (bf16*) (ws + 25*MB + 512*1024);
  float* cc      = (float*)(ws + 26*MB);        // 4 KB
  float* vqd     = (float*)(ws + 26*MB + 64*1024);
  int*   vqn     = (int*)  (ws + 26*MB + 96*1024);
  int*   idx     = (int*)  (ws + 26*MB + 128*1024);
  float* lossacc = (float*)(ws + 26*MB + 160*1024);
  float* out     = (float*)d_out;

  hipMemsetAsync(lossacc, 0, 4, stream);
  k3a_cc    <<<dim3(4),     256, 0, stream>>>(codebook, cc);
  k1_conv_in<<<dim3(8,64),  256, 0, stream>>>(x, conv_in_w, conv_in_b, h_ws);
  k2_ln     <<<dim3(64),    256, 0, stream>>>(h_ws, ln_w, ln_b, hnhi, hnlo);
  k3_gemm1  <<<dim3(32,8),  256, 0, stream>>>(hnhi, hnlo, mlp_in_w, part);
  k3r       <<<dim3(256),   256, 0, stream>>>(part, mlp_in_b, z);
  k4_vq     <<<dim3(4,64),  256, 0, stream>>>(z, codebook, cc, vqd, vqn);
  k4r       <<<dim3(8),     256, 0, stream>>>(vqd, vqn, idx);
  k5a       <<<dim3(64),    256, 0, stream>>>(idx, codebook, z, zqhi, zqlo, lossacc);
  k5_gemm2  <<<dim3(128,2), 256, 0, stream>>>(zqhi, zqlo, mlp_out_w, part);
  k5r       <<<dim3(1024),  256, 0, stream>>>(part, mlp_out_b, hout);
  k6_conv_out<<<dim3(4,64), 256, 0, stream>>>(hout, h_ws, conv_out_w, conv_out_b, out);
  k7_loss   <<<dim3(1),     64, 0, stream>>>(lossacc, out + 4194304);
}